// Round 4
// baseline (375.072 us; speedup 1.0000x reference)
//
#include <hip/hip_runtime.h>

// DynamicConv2d: B=16, CIN=COUT=64, K=3, H=W=192, OH=OW=190, DEG=64, HID=256
// out[b][co][oy][ox] = sum_{ci,ky,kx} w[b][co][ci][ky][kx] * x[b][ci][oy+ky][ox+kx]
// w = (relu(deg@W1+b1)@W2+b2).reshape(B,COUT,CIN,3,3)

typedef __bf16 bf16x8 __attribute__((ext_vector_type(8)));
typedef float  f32x4  __attribute__((ext_vector_type(4)));

#define NB   16
#define CIN  64
#define COUT 64
#define HW   192
#define OHW  190
#define NPIX (HW*HW)        // 36864
#define NW2  (COUT*CIN*9)   // 36864

__device__ __forceinline__ unsigned short f2bf(float f) {
    union { float f; unsigned int u; } v; v.f = f;
    unsigned int r = v.u + 0x7FFFu + ((v.u >> 16) & 1u);   // RNE
    return (unsigned short)(r >> 16);
}

// ---------------- k1: h = relu(deg @ W1 + b1)  [16,256] ----------------
__global__ void k1_hidden(const float* __restrict__ deg, const float* __restrict__ W1,
                          const float* __restrict__ b1, float* __restrict__ h) {
    int b = blockIdx.x, j = threadIdx.x;
    float acc = b1[j];
    for (int d = 0; d < 64; ++d) acc += deg[b*64 + d] * W1[d*256 + j];
    h[b*256 + j] = fmaxf(acc, 0.f);
}

// ---------------- k2: weights = h @ W2 + b2 -> Aw[b][tap][co][ci] bf16 ----------------
// grid 1152, block 256. Each block: 32 n-values x 8 k-chunks (32 k each) + LDS reduce.
__global__ void k2_wgen(const float* __restrict__ h, const float* __restrict__ W2,
                        const float* __restrict__ b2, unsigned short* __restrict__ Aw) {
    __shared__ float hs[16*256];
    __shared__ float red[8][16][33];
    int t = threadIdx.x;
    for (int i = t; i < 16*256; i += 256) hs[i] = h[i];
    __syncthreads();

    int nl = t & 31;                 // 0..31
    int kc = t >> 5;                 // 0..7
    int n  = blockIdx.x * 32 + nl;
    float acc[16] = {};
    #pragma unroll
    for (int kk = 0; kk < 32; ++kk) {
        int k = kc*32 + kk;
        float w = W2[(size_t)k*NW2 + n];
        #pragma unroll
        for (int b = 0; b < 16; ++b) acc[b] += hs[b*256 + k] * w;
    }
    #pragma unroll
    for (int b = 0; b < 16; ++b) red[kc][b][nl] = acc[b];
    __syncthreads();

    for (int i = t; i < 512; i += 256) {
        int b  = i >> 5;
        int nn = i & 31;
        int n2 = blockIdx.x * 32 + nn;
        float s = b2[n2];
        #pragma unroll
        for (int k = 0; k < 8; ++k) s += red[k][b][nn];
        // n2 = co*576 + ci*9 + tap   (reshape order COUT,CIN,3,3)
        int co  = n2 / 576;
        int rem = n2 - co*576;
        int ci  = rem / 9;
        int tap = rem - ci*9;
        Aw[(((b*9 + tap)*COUT + co)*CIN) + ci] = f2bf(s);
    }
}

// ---------------- k3: xT[b][p][ci] bf16 = x[b][ci][p] ----------------
__global__ void k3_transpose(const float* __restrict__ x, unsigned short* __restrict__ xT) {
    __shared__ float tile[64][65];
    int b  = blockIdx.y;
    int p0 = blockIdx.x * 64;
    int t  = threadIdx.x;
    const float* xb = x + (size_t)b * CIN * NPIX;
    {
        int c  = (t & 15) * 4;   // p within tile
        int r0 = t >> 4;         // 0..15
        #pragma unroll
        for (int i = 0; i < 4; ++i) {
            int ci = r0 + 16*i;
            float4 v = *(const float4*)(xb + (size_t)ci*NPIX + p0 + c);
            tile[ci][c] = v.x; tile[ci][c+1] = v.y; tile[ci][c+2] = v.z; tile[ci][c+3] = v.w;
        }
    }
    __syncthreads();
    {
        int ci4 = (t & 15) * 4;
        int pr  = t >> 4;        // 0..15
        #pragma unroll
        for (int i = 0; i < 4; ++i) {
            int pl = pr + 16*i;
            uint2 w;
            w.x = (unsigned int)f2bf(tile[ci4  ][pl]) | ((unsigned int)f2bf(tile[ci4+1][pl]) << 16);
            w.y = (unsigned int)f2bf(tile[ci4+2][pl]) | ((unsigned int)f2bf(tile[ci4+3][pl]) << 16);
            *(uint2*)(&xT[((size_t)b*NPIX + p0 + pl)*CIN + ci4]) = w;
        }
    }
}

// ---------------- k4: MFMA conv, NO LDS ----------------
// grid 2304 (6x * 24y * 16b), block 256 (4 waves), wave = row-pair, acc covers all 64 co.
// B-fragments straight from channels-last xT: per-lane 16B load at
// pixel(l15)*128B + lg*16 + cc*64 -> wave covers 16 full 64B sectors, coalesced.
// Tap-shifted windows re-hit L1/L2; no barriers, no LDS -> pure TLP latency hiding.
__global__ __launch_bounds__(256, 4)
void k4_conv(const unsigned short* __restrict__ xT, const unsigned short* __restrict__ Aw,
             float* __restrict__ out) {
    const int tid = threadIdx.x;

    // bijective XCD swizzle: 2304 % 8 == 0, 288 consecutive tiles per XCD
    int bid = blockIdx.x;
    int wg  = (bid & 7) * 288 + (bid >> 3);
    int b   = wg / 144;
    int ry  = wg - b*144;
    int ty  = ry / 6;
    int tx  = ry - ty*6;
    const int x0 = tx * 32;
    const int y0 = ty * 8;

    const int wv  = tid >> 6;    // wave 0..3 -> rows 2wv, 2wv+1
    const int l   = tid & 63;
    const int l15 = l & 15;
    const int lg  = l >> 4;      // 0..3

    const unsigned short* Ab  = Aw + b * (9*COUT*CIN);
    const unsigned short* Al  = Ab + l15*CIN + lg*8;          // lane A base
    const unsigned short* xTb = xT + (size_t)b * NPIX * CIN;

    f32x4 acc[4][4] = {};        // [m co-group][n = r*2+xb2]

    #pragma unroll
    for (int tap = 0; tap < 9; ++tap) {
        const int ky = tap / 3, kx = tap - 3*(tap/3);
        #pragma unroll
        for (int cc = 0; cc < 2; ++cc) {
            bf16x8 a[4], bb[4];
            #pragma unroll
            for (int r = 0; r < 2; ++r)
                #pragma unroll
                for (int xb2 = 0; xb2 < 2; ++xb2) {
                    int gy = y0 + 2*wv + r + ky;   if (gy > 191) gy = 191;
                    int gx = x0 + xb2*16 + l15 + kx; if (gx > 191) gx = 191;
                    bb[r*2 + xb2] = *(const bf16x8*)(xTb + ((size_t)(gy*HW + gx))*CIN + cc*32 + lg*8);
                }
            #pragma unroll
            for (int m = 0; m < 4; ++m)
                a[m] = *(const bf16x8*)(Al + tap*4096 + m*1024 + cc*32);
            #pragma unroll
            for (int m = 0; m < 4; ++m)
                #pragma unroll
                for (int n = 0; n < 4; ++n)
                    acc[m][n] = __builtin_amdgcn_mfma_f32_16x16x32_bf16(a[m], bb[n], acc[m][n], 0, 0, 0);
        }
    }

    // ---- epilogue: D col = lane&15 (spatial), row = (lane>>4)*4+j (co) ----
    #pragma unroll
    for (int m = 0; m < 4; ++m)
        #pragma unroll
        for (int r = 0; r < 2; ++r)
            #pragma unroll
            for (int xb2 = 0; xb2 < 2; ++xb2) {
                int oy = y0 + 2*wv + r;
                int ox = x0 + xb2*16 + l15;
                if (oy < OHW && ox < OHW) {
                    f32x4 v = acc[m][r*2 + xb2];
                    #pragma unroll
                    for (int j = 0; j < 4; ++j) {
                        int co = m*16 + lg*4 + j;
                        out[((size_t)(b*COUT + co)*OHW + oy)*OHW + ox] = v[j];
                    }
                }
            }
}

extern "C" void kernel_launch(void* const* d_in, const int* in_sizes, int n_in,
                              void* d_out, int out_size, void* d_ws, size_t ws_size,
                              hipStream_t stream) {
    const float* x   = (const float*)d_in[0];
    const float* deg = (const float*)d_in[1];
    const float* W1  = (const float*)d_in[2];
    const float* b1  = (const float*)d_in[3];
    const float* W2  = (const float*)d_in[4];
    const float* b2  = (const float*)d_in[5];
    float* out = (float*)d_out;

    const size_t off_h  = 0;                       // 16 KB
    const size_t off_Aw = 16 * 1024;
    const size_t off_xT = off_Aw + (size_t)NB*9*COUT*CIN*2;   // 16B aligned
    float* h           = (float*)((char*)d_ws + off_h);
    unsigned short* Aw = (unsigned short*)((char*)d_ws + off_Aw);
    unsigned short* xT = (unsigned short*)((char*)d_ws + off_xT);

    k1_hidden<<<16, 256, 0, stream>>>(deg, W1, b1, h);
    k2_wgen<<<NW2/32, 256, 0, stream>>>(h, W2, b2, Aw);
    k3_transpose<<<dim3(NPIX/64, NB), 256, 0, stream>>>(x, xT);
    k4_conv<<<2304, 256, 0, stream>>>(xT, Aw, out);
}

// Round 5
// 181.231 us; speedup vs baseline: 2.0696x; 2.0696x over previous
//
#include <hip/hip_runtime.h>

// DynamicConv2d: B=16, CIN=COUT=64, K=3, H=W=192, OH=OW=190, DEG=64, HID=256
// out[b][co][oy][ox] = sum_{ci,ky,kx} w[b][co][ci][ky][kx] * x[b][ci][oy+ky][ox+kx]
// w = (relu(deg@W1+b1)@W2+b2).reshape(B,COUT,CIN,3,3)

typedef __bf16 bf16x8 __attribute__((ext_vector_type(8)));
typedef float  f32x4  __attribute__((ext_vector_type(4)));

#define NB   16
#define CIN  64
#define COUT 64
#define HW   192
#define OHW  190
#define NPIX (HW*HW)        // 36864
#define NW2  (COUT*CIN*9)   // 36864

__device__ __forceinline__ unsigned short f2bf(float f) {
    union { float f; unsigned int u; } v; v.f = f;
    unsigned int r = v.u + 0x7FFFu + ((v.u >> 16) & 1u);   // RNE
    return (unsigned short)(r >> 16);
}

// async global->LDS, 16B per lane. LDS dest: wave-uniform base + lane*16.
__device__ __forceinline__ void async_copy16(const void* gsrc, void* ldst) {
    __builtin_amdgcn_global_load_lds(
        (const __attribute__((address_space(1))) unsigned int*)gsrc,
        (__attribute__((address_space(3))) unsigned int*)ldst, 16, 0, 0);
}

// ---------------- k1: h = relu(deg @ W1 + b1)  [16,256] ----------------
__global__ void k1_hidden(const float* __restrict__ deg, const float* __restrict__ W1,
                          const float* __restrict__ b1, float* __restrict__ h) {
    int b = blockIdx.x, j = threadIdx.x;
    float acc = b1[j];
    for (int d = 0; d < 64; ++d) acc += deg[b*64 + d] * W1[d*256 + j];
    h[b*256 + j] = fmaxf(acc, 0.f);
}

// ---------------- k2: weights = h @ W2 + b2 -> Aw[b][tap][co][ci] bf16 ----------------
__global__ void k2_wgen(const float* __restrict__ h, const float* __restrict__ W2,
                        const float* __restrict__ b2, unsigned short* __restrict__ Aw) {
    __shared__ float hs[16*256];
    __shared__ float red[8][16][33];
    int t = threadIdx.x;
    for (int i = t; i < 16*256; i += 256) hs[i] = h[i];
    __syncthreads();

    int nl = t & 31;                 // 0..31
    int kc = t >> 5;                 // 0..7
    int n  = blockIdx.x * 32 + nl;
    float acc[16] = {};
    #pragma unroll
    for (int kk = 0; kk < 32; ++kk) {
        int k = kc*32 + kk;
        float w = W2[(size_t)k*NW2 + n];
        #pragma unroll
        for (int b = 0; b < 16; ++b) acc[b] += hs[b*256 + k] * w;
    }
    #pragma unroll
    for (int b = 0; b < 16; ++b) red[kc][b][nl] = acc[b];
    __syncthreads();

    for (int i = t; i < 512; i += 256) {
        int b  = i >> 5;
        int nn = i & 31;
        int n2 = blockIdx.x * 32 + nn;
        float s = b2[n2];
        #pragma unroll
        for (int k = 0; k < 8; ++k) s += red[k][b][nn];
        int co  = n2 / 576;
        int rem = n2 - co*576;
        int ci  = rem / 9;
        int tap = rem - ci*9;
        Aw[(((b*9 + tap)*COUT + co)*CIN) + ci] = f2bf(s);
    }
}

// ---------------- k3: xT[b][p][ci] bf16 = x[b][ci][p] ----------------
__global__ void k3_transpose(const float* __restrict__ x, unsigned short* __restrict__ xT) {
    __shared__ float tile[64][65];
    int b  = blockIdx.y;
    int p0 = blockIdx.x * 64;
    int t  = threadIdx.x;
    const float* xb = x + (size_t)b * CIN * NPIX;
    {
        int c  = (t & 15) * 4;
        int r0 = t >> 4;
        #pragma unroll
        for (int i = 0; i < 4; ++i) {
            int ci = r0 + 16*i;
            float4 v = *(const float4*)(xb + (size_t)ci*NPIX + p0 + c);
            tile[ci][c] = v.x; tile[ci][c+1] = v.y; tile[ci][c+2] = v.z; tile[ci][c+3] = v.w;
        }
    }
    __syncthreads();
    {
        int ci4 = (t & 15) * 4;
        int pr  = t >> 4;
        #pragma unroll
        for (int i = 0; i < 4; ++i) {
            int pl = pr + 16*i;
            uint2 w;
            w.x = (unsigned int)f2bf(tile[ci4  ][pl]) | ((unsigned int)f2bf(tile[ci4+1][pl]) << 16);
            w.y = (unsigned int)f2bf(tile[ci4+2][pl]) | ((unsigned int)f2bf(tile[ci4+3][pl]) << 16);
            *(uint2*)(&xT[((size_t)b*NPIX + p0 + pl)*CIN + ci4]) = w;
        }
    }
}

// ---------------- k4: strip MFMA conv, deep-pipelined ----------------
// grid 768 (16b x 8strip x 6tx), block 512 (8 waves = 2 co-half x 4 row-pair).
// Strip = 24 rows x 32 cols = 3 subtiles of 8x32. A (all 9 taps, own co-half) in
// registers, loaded once. x staged per subtile in double-buffered LDS via
// global_load_lds (pre-swizzled source, linear dest). stage(s+1) issued BEFORE
// compute(s); one __syncthreads per subtile (T3 2-phase minimum pattern).
__global__ __launch_bounds__(512, 2)
void k4_conv(const unsigned short* __restrict__ xT, const unsigned short* __restrict__ Aw,
             float* __restrict__ out) {
    __shared__ unsigned short xs[2][10*34*64];   // 2 x 43520 B
    const int tid = threadIdx.x;

    // bijective XCD swizzle: 768 % 8 == 0, 96 consecutive wg per XCD
    int bid = blockIdx.x;
    int wg  = (bid & 7) * 96 + (bid >> 3);
    int b     = wg / 48;
    int rem   = wg - b*48;
    int strip = rem / 6;
    int tx    = rem - strip*6;
    const int x0 = tx * 32;
    const int y0 = strip * 24;

    const int wv  = tid >> 6;      // 0..7
    const int mh  = wv >> 2;       // co half 0..1
    const int rr  = wv & 3;        // row-pair 0..3 within 8-row subtile
    const int l   = tid & 63;
    const int l15 = l & 15;
    const int lg  = l >> 4;        // 0..3

    const unsigned short* xTb = xT + (size_t)b * NPIX * CIN;

    // ---- A fragments: all 9 taps for this wave's co-half, loaded once ----
    const unsigned short* Ab = Aw + b * (9*COUT*CIN);
    bf16x8 a[9][2][2];   // [tap][cc][m]
    #pragma unroll
    for (int tap = 0; tap < 9; ++tap)
        #pragma unroll
        for (int cc = 0; cc < 2; ++cc)
            #pragma unroll
            for (int m = 0; m < 2; ++m)
                a[tap][cc][m] = *(const bf16x8*)(Ab + tap*4096 + (mh*32 + m*16 + l15)*CIN + cc*32 + lg*8);

    // ---- stage subtile ss into buffer buf (10 rows x 34 px x 64 ci) ----
    #define STAGE(buf, ss)                                                              \
        do {                                                                            \
            int ybase = y0 + 8*(ss);                                                    \
            _Pragma("unroll")                                                           \
            for (int it = 0; it < 6; ++it) {                                            \
                int sl = it*512 + tid;                                                  \
                if (sl < 2720) {                                                        \
                    int swc = sl & 7;                                                   \
                    int t2  = sl >> 3;                                                  \
                    int gyl = t2 / 34;                                                  \
                    int gxl = t2 - gyl*34;                                              \
                    int gy = ybase + gyl; if (gy > 191) gy = 191;                       \
                    int gx = x0 + gxl;    if (gx > 191) gx = 191;                       \
                    const void* src = xTb + ((size_t)(gy*HW + gx))*CIN                  \
                                      + ((swc ^ (gx & 7)) * 8);                         \
                    void* dst = &xs[buf][(it*512 + wv*64) * 8];                         \
                    async_copy16(src, dst);                                             \
                }                                                                       \
            }                                                                           \
        } while (0)

    STAGE(0, 0);
    __syncthreads();     // drains vmcnt(0): xs[0] + a[] ready

    #pragma unroll
    for (int ss = 0; ss < 3; ++ss) {
        const int cbuf = ss & 1;
        if (ss < 2) STAGE(cbuf ^ 1, ss + 1);    // issue next-tile loads first (T3)

        f32x4 acc[2][4] = {};    // [m][n = r*2+xb2]
        #pragma unroll
        for (int tap = 0; tap < 9; ++tap) {
            const int ky = tap / 3, kx = tap - 3*(tap/3);
            #pragma unroll
            for (int cc = 0; cc < 2; ++cc) {
                bf16x8 bb[4];
                #pragma unroll
                for (int r = 0; r < 2; ++r)
                    #pragma unroll
                    for (int xb2 = 0; xb2 < 2; ++xb2) {
                        int gyl = rr*2 + r + ky;
                        int gxl = xb2*16 + l15 + kx;
                        int pch = (cc*4 + lg) ^ (gxl & 7);
                        bb[r*2 + xb2] = *(const bf16x8*)(&xs[cbuf][((gyl*34 + gxl)*8 + pch)*8]);
                    }
                #pragma unroll
                for (int m = 0; m < 2; ++m)
                    #pragma unroll
                    for (int n = 0; n < 4; ++n)
                        acc[m][n] = __builtin_amdgcn_mfma_f32_16x16x32_bf16(a[tap][cc][m], bb[n], acc[m][n], 0, 0, 0);
            }
        }

        // ---- epilogue for subtile ss: D col = lane&15 (ox), row = lg*4+j (co) ----
        #pragma unroll
        for (int m = 0; m < 2; ++m)
            #pragma unroll
            for (int r = 0; r < 2; ++r)
                #pragma unroll
                for (int xb2 = 0; xb2 < 2; ++xb2) {
                    int oy = y0 + 8*ss + rr*2 + r;
                    int ox = x0 + xb2*16 + l15;
                    if (oy < OHW && ox < OHW) {
                        f32x4 v = acc[m][r*2 + xb2];
                        #pragma unroll
                        for (int j = 0; j < 4; ++j) {
                            int co = mh*32 + m*16 + lg*4 + j;
                            out[((size_t)(b*COUT + co)*OHW + oy)*OHW + ox] = v[j];
                        }
                    }
                }

        __syncthreads();   // all reads of xs[cbuf] done; gll into xs[cbuf^1] drained
    }
    #undef STAGE
}

extern "C" void kernel_launch(void* const* d_in, const int* in_sizes, int n_in,
                              void* d_out, int out_size, void* d_ws, size_t ws_size,
                              hipStream_t stream) {
    const float* x   = (const float*)d_in[0];
    const float* deg = (const float*)d_in[1];
    const float* W1  = (const float*)d_in[2];
    const float* b1  = (const float*)d_in[3];
    const float* W2  = (const float*)d_in[4];
    const float* b2  = (const float*)d_in[5];
    float* out = (float*)d_out;

    const size_t off_h  = 0;                       // 16 KB
    const size_t off_Aw = 16 * 1024;
    const size_t off_xT = off_Aw + (size_t)NB*9*COUT*CIN*2;   // 16B aligned
    float* h           = (float*)((char*)d_ws + off_h);
    unsigned short* Aw = (unsigned short*)((char*)d_ws + off_Aw);
    unsigned short* xT = (unsigned short*)((char*)d_ws + off_xT);

    k1_hidden<<<16, 256, 0, stream>>>(deg, W1, b1, h);
    k2_wgen<<<NW2/32, 256, 0, stream>>>(h, W2, b2, Aw);
    k3_transpose<<<dim3(NPIX/64, NB), 256, 0, stream>>>(x, xT);
    k4_conv<<<768, 512, 0, stream>>>(xT, Aw, out);
}